// Round 4
// baseline (121.146 us; speedup 1.0000x reference)
//
#include <hip/hip_runtime.h>
#include <hip/hip_fp16.h>

#define IMH 1024
#define IMW 1024
#define GD 8
#define GH 16
#define GW 16
#define NC 12
#define NZB 7     // z-pair entries zb in [0,6]; entry = {z=zb coeffs, z=zb+1 coeffs}
#define ENT 24    // halfs per (x,zb) entry
#define ROWS 4

// LDS: f16 z-pair-duplicated y-lerped grid. Entry (x,zb) = 48 B, 16B-aligned.
// Gather = 3 ds_read_b128 per x-corner (both z planes in one contiguous read).
// Bank math: dword idx = 12*(7x+zb)+w; 12k mod 32 tiles 8 disjoint 4-bank
// quads; per wave <=2 distinct x and distinct zb -> <=2 addrs per quad ->
// <=2-way conflicts (free, m136).
__global__ __launch_bounds__(256) void bsa_kernel(
    const float* __restrict__ grid,
    const float* __restrict__ guide,
    const float* __restrict__ image,
    float* __restrict__ out)
{
    const int y0  = blockIdx.x * ROWS;
    const int b   = blockIdx.y;
    const int tid = threadIdx.x;

    __shared__ __align__(16) __half sH[2][GW][NZB][ENT];   // 10.5 KB
    __half* const sbase = &sH[0][0][0][0];
    const int SBUF = GW * NZB * ENT;                       // 2688 halfs

    const float* gb = grid + (size_t)b * NC * GD * GH * GW;

    // ---- hoisted staging indices: 1536 y-lerp values / 256 thr = 6 each
    int gsrc[6], sx[6], sz[6], sc[6];
    #pragma unroll
    for (int k = 0; k < 6; ++k) {
        const int i = tid + 256 * k;
        sx[k] = i & (GW - 1);
        sz[k] = (i >> 4) & (GD - 1);
        sc[k] = i >> 7;
        gsrc[k] = ((sc[k] * GD + sz[k]) * GH) * GW + sx[k];
    }

    // ---- hoisted per-thread x-interp (constant across rows)
    int   xo0[4], xo1[4];      // half-offsets of x-corner entries
    float wx0v[4], wx1v[4];
    #pragma unroll
    for (int p = 0; p < 4; ++p) {
        const int   x   = tid + 256 * p;
        const float gx  = (x + 0.5f) * ((float)GW / IMW);
        const float fxf = floorf(gx - 0.5f);
        const float tx  = gx - 0.5f - fxf;
        const int   fx  = (int)fxf;
        const int   ix0 = min(GW - 1, max(0, fx));
        const int   ix1 = min(GW - 1, max(0, fx + 1));
        xo0[p] = ix0 * (NZB * ENT);
        xo1[p] = ix1 * (NZB * ENT);
        wx0v[p] = 1.0f - tx;
        wx1v[p] = tx;
    }

    // ---- stage row y0 into buffer 0
    {
        const float gy  = (y0 + 0.5f) * ((float)GH / IMH);
        const float fyf = floorf(gy - 0.5f);
        const float ty  = gy - 0.5f - fyf;
        const int   fy  = (int)fyf;
        const int   iy0 = min(GH - 1, max(0, fy));
        const int   iy1 = min(GH - 1, max(0, fy + 1));
        #pragma unroll
        for (int k = 0; k < 6; ++k) {
            const float v0 = gb[gsrc[k] + iy0 * GW];
            const float v1 = gb[gsrc[k] + iy1 * GW];
            const __half h = __float2half(v0 + ty * (v1 - v0));
            const int x = sx[k], z = sz[k], c = sc[k];
            if (z < NZB) sH[0][x][z][c] = h;            // as z-lo of entry zb=z
            if (z > 0)   sH[0][x][z - 1][NC + c] = h;   // as z-hi of entry zb=z-1
        }
    }
    __syncthreads();

    const size_t plane = (size_t)IMH * IMW;

    #pragma unroll
    for (int j = 0; j < ROWS; ++j) {
        // -- raw staging loads for row j+1 kept in flight during compute
        float nv0[6], nv1[6], nty = 0.0f;
        if (j + 1 < ROWS) {
            const int   yn  = y0 + j + 1;
            const float gy  = (yn + 0.5f) * ((float)GH / IMH);
            const float fyf = floorf(gy - 0.5f);
            nty = gy - 0.5f - fyf;
            const int fy  = (int)fyf;
            const int iy0 = min(GH - 1, max(0, fy));
            const int iy1 = min(GH - 1, max(0, fy + 1));
            #pragma unroll
            for (int k = 0; k < 6; ++k) {
                nv0[k] = gb[gsrc[k] + iy0 * GW];
                nv1[k] = gb[gsrc[k] + iy1 * GW];
            }
        }

        const int y = y0 + j;
        const float* gp = guide + ((size_t)b * IMH + y) * IMW;
        const float* ip = image + ((size_t)b * 3 * IMH + y) * IMW;
        float*       op = out   + ((size_t)b * 3 * IMH + y) * IMW;
        const __half* S = sbase + (j & 1) * SBUF;

        #pragma unroll
        for (int p = 0; p < 4; ++p) {
            const int x = tid + 256 * p;

            const float gv = gp[x];
            const float rv = ip[x];
            const float g2 = ip[x + plane];
            const float bv = ip[x + 2 * plane];

            // z position -> pair index zb + folded clamp weights (az, bz)
            const float gz  = gv * (float)GD;
            const float fzf = floorf(gz - 0.5f);
            const float tz  = gz - 0.5f - fzf;
            const int   fzi = (int)fzf;
            const int   zb  = min(NZB - 1, max(0, fzi));
            const float az  = (fzi < 0) ? 1.0f : ((fzi > NZB - 1) ? 0.0f : 1.0f - tz);
            const float bz  = (fzi < 0) ? 0.0f : ((fzi > NZB - 1) ? 1.0f : tz);

            const __half2 wa0 = __float2half2_rn(az * wx0v[p]);
            const __half2 wb0 = __float2half2_rn(bz * wx0v[p]);
            const __half2 wa1 = __float2half2_rn(az * wx1v[p]);
            const __half2 wb1 = __float2half2_rn(bz * wx1v[p]);

            const __half* e0 = S + xo0[p] + zb * ENT;
            const __half* e1 = S + xo1[p] + zb * ENT;

            __half2 A[12], B[12];
            *(uint4*)(A + 0) = *(const uint4*)(e0);
            *(uint4*)(A + 4) = *(const uint4*)(e0 + 8);
            *(uint4*)(A + 8) = *(const uint4*)(e0 + 16);
            *(uint4*)(B + 0) = *(const uint4*)(e1);
            *(uint4*)(B + 4) = *(const uint4*)(e1 + 8);
            *(uint4*)(B + 8) = *(const uint4*)(e1 + 16);

            __half2 cl[6];
            #pragma unroll
            for (int d = 0; d < 6; ++d) {
                __half2 t = __hmul2(wa0, A[d]);
                t = __hfma2(wb0, A[d + 6], t);
                t = __hfma2(wa1, B[d], t);
                t = __hfma2(wb1, B[d + 6], t);
                cl[d] = t;
            }

            float res[3];
            #pragma unroll
            for (int i = 0; i < 3; ++i) {
                const float c0 = __low2float(cl[2 * i]);
                const float c1 = __high2float(cl[2 * i]);
                const float c2 = __low2float(cl[2 * i + 1]);
                const float c3 = __high2float(cl[2 * i + 1]);
                res[i] = fmaf(c0, rv, fmaf(c1, g2, fmaf(c2, bv, c3)));
            }

            op[x]             = res[0];
            op[x + plane]     = res[1];
            op[x + 2 * plane] = res[2];
        }

        // -- finish staging row j+1 into the other buffer
        if (j + 1 < ROWS) {
            __half* D = sbase + ((j + 1) & 1) * SBUF;
            #pragma unroll
            for (int k = 0; k < 6; ++k) {
                const __half h = __float2half(nv0[k] + nty * (nv1[k] - nv0[k]));
                const int x = sx[k], z = sz[k], c = sc[k];
                if (z < NZB) D[(x * NZB + z) * ENT + c] = h;
                if (z > 0)   D[(x * NZB + (z - 1)) * ENT + NC + c] = h;
            }
        }
        __syncthreads();
    }
}

extern "C" void kernel_launch(void* const* d_in, const int* in_sizes, int n_in,
                              void* d_out, int out_size, void* d_ws, size_t ws_size,
                              hipStream_t stream) {
    const float* grid  = (const float*)d_in[0];
    const float* guide = (const float*)d_in[1];
    const float* image = (const float*)d_in[2];
    float* out = (float*)d_out;

    const int B = in_sizes[1] / (IMH * IMW);   // guide is (B, H, W)
    dim3 g(IMH / ROWS, B);
    bsa_kernel<<<g, 256, 0, stream>>>(grid, guide, image, out);
}

// Round 5
// 114.406 us; speedup vs baseline: 1.0589x; 1.0589x over previous
//
#include <hip/hip_runtime.h>
#include <hip/hip_fp16.h>

#define IMH 1024
#define IMW 1024
#define GD 8
#define GH 16
#define GW 16
#define NC 12
#define NZB 7     // z-pair entries zb in [0,6]; entry = {z=zb coeffs, z=zb+1 coeffs}
#define ENT 24    // halfs per (x,zb) entry (48 B, 16B-aligned)
#define ROWS 4

// Structure rationale (R5): ONE barrier per block. All ROWS rows' y-lerped
// grids staged up-front; compute is barrier-free so the compiler pipelines
// guide/image loads across rows with fine-grained vmcnt instead of the
// per-row vmcnt(0) drain that __syncthreads forces (m97 barrier lesson).
// fy is uniform for any 4-aligned row group (cell boundary at y%64==32),
// so raw grid loads happen once per block.
// LDS gather: f16 z-pair-duplicated entries -> 6 ds_read_b128 per pixel.
// Bank math: entry dword = 12*(7x+zb); 12m mod 32 tiles 8 disjoint 4-bank
// quads; wave spans <=2 x-cells -> <=2 addrs/quad -> conflict-free (m136).
__global__ __launch_bounds__(256, 4) void bsa_kernel(
    const float* __restrict__ grid,
    const float* __restrict__ guide,
    const float* __restrict__ image,
    float* __restrict__ out)
{
    const int y0  = blockIdx.x * ROWS;
    const int b   = blockIdx.y;
    const int tid = threadIdx.x;

    __shared__ __align__(16) __half sH[ROWS][GW][NZB][ENT];   // 21 KB

    const float* gb = grid + (size_t)b * NC * GD * GH * GW;

    // ---- hoisted per-thread x-interp (constant across rows)
    int   xo0[4], xo1[4];
    float wx0v[4], wx1v[4];
    #pragma unroll
    for (int p = 0; p < 4; ++p) {
        const int   x   = tid + 256 * p;
        const float gx  = (x + 0.5f) * ((float)GW / IMW);
        const float fxf = floorf(gx - 0.5f);
        const float tx  = gx - 0.5f - fxf;
        const int   fx  = (int)fxf;
        xo0[p] = min(GW - 1, max(0, fx)) * (NZB * ENT);
        xo1[p] = min(GW - 1, max(0, fx + 1)) * (NZB * ENT);
        wx0v[p] = 1.0f - tx;
        wx1v[p] = tx;
    }

    // ---- stage all ROWS rows, one barrier
    {
        // 256 threads = 16x * 8z * 2 c-halves
        const int q  = tid >> 1;
        const int x  = q & (GW - 1);
        const int z  = q >> 4;             // [0,8)
        const int c0 = (tid & 1) * 6;

        // fy uniform across the 4-aligned row group
        const float gy0 = (y0 + 0.5f) * ((float)GH / IMH);
        const int   fy  = (int)floorf(gy0 - 0.5f);
        const int   iy0 = min(GH - 1, max(0, fy));
        const int   iy1 = min(GH - 1, max(0, fy + 1));

        float v0[6], v1[6];
        #pragma unroll
        for (int c = 0; c < 6; ++c) {
            const int cc = c0 + c;
            v0[c] = gb[((cc * GD + z) * GH + iy0) * GW + x];
            v1[c] = gb[((cc * GD + z) * GH + iy1) * GW + x];
        }

        #pragma unroll
        for (int r = 0; r < ROWS; ++r) {
            const float ty = (y0 + r + 0.5f) * ((float)GH / IMH) - 0.5f - (float)fy;
            __half2 hv[3];
            #pragma unroll
            for (int d = 0; d < 3; ++d) {
                const float a = v0[2*d]   + ty * (v1[2*d]   - v0[2*d]);
                const float c = v0[2*d+1] + ty * (v1[2*d+1] - v0[2*d+1]);
                hv[d] = __halves2half2(__float2half(a), __float2half(c));
            }
            if (z < NZB) {
                __half2* dst = (__half2*)&sH[r][x][z][c0];
                dst[0] = hv[0]; dst[1] = hv[1]; dst[2] = hv[2];
            }
            if (z > 0) {
                __half2* dst = (__half2*)&sH[r][x][z - 1][NC + c0];
                dst[0] = hv[0]; dst[1] = hv[1]; dst[2] = hv[2];
            }
        }
    }
    __syncthreads();   // the ONLY barrier

    const size_t plane = (size_t)IMH * IMW;

    #pragma unroll
    for (int r = 0; r < ROWS; ++r) {
        const int y = y0 + r;
        const float* gp = guide + ((size_t)b * IMH + y) * IMW;
        const float* ip = image + ((size_t)b * 3 * IMH + y) * IMW;
        float*       op = out   + ((size_t)b * 3 * IMH + y) * IMW;
        const __half* S = &sH[r][0][0][0];

        #pragma unroll
        for (int p = 0; p < 4; ++p) {
            const int x = tid + 256 * p;

            const float gv = gp[x];
            const float rv = ip[x];
            const float g2 = ip[x + plane];
            const float bv = ip[x + 2 * plane];

            // z -> pair index zb + folded clamp weights
            const float gz  = gv * (float)GD;
            const float fzf = floorf(gz - 0.5f);
            const float tz  = gz - 0.5f - fzf;
            const int   fzi = (int)fzf;
            const int   zb  = min(NZB - 1, max(0, fzi));
            const float az  = (fzi < 0) ? 1.0f : ((fzi > NZB - 1) ? 0.0f : 1.0f - tz);
            const float bz  = (fzi < 0) ? 0.0f : ((fzi > NZB - 1) ? 1.0f : tz);

            const __half2 wa0 = __float2half2_rn(az * wx0v[p]);
            const __half2 wb0 = __float2half2_rn(bz * wx0v[p]);
            const __half2 wa1 = __float2half2_rn(az * wx1v[p]);
            const __half2 wb1 = __float2half2_rn(bz * wx1v[p]);

            const __half* e0 = S + xo0[p] + zb * ENT;
            const __half* e1 = S + xo1[p] + zb * ENT;

            __half2 A[12], B[12];
            *(uint4*)(A + 0) = *(const uint4*)(e0);
            *(uint4*)(A + 4) = *(const uint4*)(e0 + 8);
            *(uint4*)(A + 8) = *(const uint4*)(e0 + 16);
            *(uint4*)(B + 0) = *(const uint4*)(e1);
            *(uint4*)(B + 4) = *(const uint4*)(e1 + 8);
            *(uint4*)(B + 8) = *(const uint4*)(e1 + 16);

            __half2 cl[6];
            #pragma unroll
            for (int d = 0; d < 6; ++d) {
                __half2 t = __hmul2(wa0, A[d]);
                t = __hfma2(wb0, A[d + 6], t);
                t = __hfma2(wa1, B[d], t);
                t = __hfma2(wb1, B[d + 6], t);
                cl[d] = t;
            }

            float res[3];
            #pragma unroll
            for (int i = 0; i < 3; ++i) {
                const float c0f = __low2float(cl[2 * i]);
                const float c1f = __high2float(cl[2 * i]);
                const float c2f = __low2float(cl[2 * i + 1]);
                const float c3f = __high2float(cl[2 * i + 1]);
                res[i] = fmaf(c0f, rv, fmaf(c1f, g2, fmaf(c2f, bv, c3f)));
            }

            op[x]             = res[0];
            op[x + plane]     = res[1];
            op[x + 2 * plane] = res[2];
        }
    }
}

extern "C" void kernel_launch(void* const* d_in, const int* in_sizes, int n_in,
                              void* d_out, int out_size, void* d_ws, size_t ws_size,
                              hipStream_t stream) {
    const float* grid  = (const float*)d_in[0];
    const float* guide = (const float*)d_in[1];
    const float* image = (const float*)d_in[2];
    float* out = (float*)d_out;

    const int B = in_sizes[1] / (IMH * IMW);   // guide is (B, H, W)
    dim3 g(IMH / ROWS, B);
    bsa_kernel<<<g, 256, 0, stream>>>(grid, guide, image, out);
}